// Round 3
// baseline (584.068 us; speedup 1.0000x reference)
//
#include <hip/hip_runtime.h>

// Problem: T=8, N=256, F=128. All inputs/outputs FLOAT32 (per reference).
// Decomposition: y[t,i,j,f] = A[t,i,f] + B[t,j,f],
//   A = x @ w[:, :F]^T, B = x @ w[:, F:]^T   (per branch).
// BN train-mode stats decompose onto A/B:
//   mean = (SA+SB)/(T*N),  E[y^2] = (QA+QB)/(T*N) + 2*sum_t SA_t.SB_t/(T*N^2)
// Final kernel streams 537 MB of f32 output (write-roofline ~85 us).

#define TT 8
#define NN 256
#define FF 128
// rows = T*N = 2048; per-array ws region = 2048*128 = 262144 floats

typedef float vf2 __attribute__((ext_vector_type(2)));  // nontemporal-store-able

// ---------------------------------------------------------------------------
// Kernel 1: A1,B1,A2,B2 [2048 rows][128 f] from f32 x and w1/w2.
// 512 blocks x 128 threads; block = 4 rows; thread = output channel f.
// ---------------------------------------------------------------------------
__global__ __launch_bounds__(128) void k_matmul(
    const float* __restrict__ x,    // [2048][128]
    const float* __restrict__ w1,   // [128][256]
    const float* __restrict__ w2,   // [128][256]
    float* __restrict__ ws)
{
    __shared__ float xs[4][FF];
    const int tid = threadIdx.x;
    const int row0 = blockIdx.x * 4;

    // stage 4 x-rows into LDS: 512 floats = 128 float4, one per thread
    {
        const float4* xv = (const float4*)(x + row0 * FF);
        float4 q = xv[tid];
        ((float4*)&xs[0][0])[tid] = q;
    }
    __syncthreads();

    const int f = tid;
    float acc0[4] = {0,0,0,0}, acc1[4] = {0,0,0,0};
    float acc2[4] = {0,0,0,0}, acc3[4] = {0,0,0,0};
    const float4* w1v = (const float4*)w1;  // row f = 64 float4 (32 A-half, 32 B-half)
    const float4* w2v = (const float4*)w2;

    #pragma unroll 8
    for (int c4 = 0; c4 < 32; ++c4) {
        float4 qa1 = w1v[f * 64 + c4];
        float4 qb1 = w1v[f * 64 + 32 + c4];
        float4 qa2 = w2v[f * 64 + c4];
        float4 qb2 = w2v[f * 64 + 32 + c4];
        const int c = c4 * 4;
        #pragma unroll
        for (int r = 0; r < 4; ++r) {
            float x0 = xs[r][c], x1 = xs[r][c + 1], x2 = xs[r][c + 2], x3 = xs[r][c + 3];
            acc0[r] = fmaf(x0, qa1.x, fmaf(x1, qa1.y, fmaf(x2, qa1.z, fmaf(x3, qa1.w, acc0[r]))));
            acc1[r] = fmaf(x0, qb1.x, fmaf(x1, qb1.y, fmaf(x2, qb1.z, fmaf(x3, qb1.w, acc1[r]))));
            acc2[r] = fmaf(x0, qa2.x, fmaf(x1, qa2.y, fmaf(x2, qa2.z, fmaf(x3, qa2.w, acc2[r]))));
            acc3[r] = fmaf(x0, qb2.x, fmaf(x1, qb2.y, fmaf(x2, qb2.z, fmaf(x3, qb2.w, acc3[r]))));
        }
    }

    float* A1 = ws;
    float* B1 = ws + 262144;
    float* A2 = ws + 524288;
    float* B2 = ws + 786432;
    #pragma unroll
    for (int r = 0; r < 4; ++r) {
        int row = row0 + r;
        A1[row * FF + f] = acc0[r];
        B1[row * FF + f] = acc1[r];
        A2[row * FF + f] = acc2[r];
        B2[row * FF + f] = acc3[r];
    }
}

// ---------------------------------------------------------------------------
// Kernel 2a: per-(array, t) channel sums and sum-of-squares over n.
// grid = 32 (t in [0,8) x arr in [0,4)), block = 256.
// ---------------------------------------------------------------------------
__global__ __launch_bounds__(256) void k_stats(
    const float* __restrict__ ab,
    float* __restrict__ sums, float* __restrict__ sumsq)
{
    const int bx = blockIdx.x;
    const int t = bx & 7, arr = bx >> 3;
    const float* A = ab + arr * 262144 + t * NN * FF;
    const int tid = threadIdx.x;
    const int f = tid & 127, h = tid >> 7;
    float s = 0.f, q = 0.f;
    for (int n = h; n < NN; n += 2) {
        float v = A[n * FF + f];
        s += v;
        q = fmaf(v, v, q);
    }
    __shared__ float ls[256], lq[256];
    ls[tid] = s; lq[tid] = q;
    __syncthreads();
    if (tid < 128) {
        sums [(arr * 8 + t) * FF + f] = ls[tid] + ls[tid + 128];
        sumsq[(arr * 8 + t) * FF + f] = lq[tid] + lq[tid + 128];
    }
}

// ---------------------------------------------------------------------------
// Kernel 2b: fold BN (train-mode, biased var) into per-channel scale/bias.
// 1 block x 256 threads (branch = tid>>7, f = tid&127).
// ---------------------------------------------------------------------------
__global__ __launch_bounds__(256) void k_scale(
    const float* __restrict__ sums, const float* __restrict__ sumsq,
    const float* __restrict__ g1, const float* __restrict__ b1,
    const float* __restrict__ g2, const float* __restrict__ b2,
    float* __restrict__ scale, float* __restrict__ bias)
{
    const int tid = threadIdx.x;
    const int br = tid >> 7, f = tid & 127;
    const int aA = 2 * br, aB = 2 * br + 1;
    float SA = 0.f, SB = 0.f, QA = 0.f, QB = 0.f, cross = 0.f;
    #pragma unroll
    for (int t = 0; t < TT; ++t) {
        float sa = sums[(aA * 8 + t) * FF + f];
        float sb = sums[(aB * 8 + t) * FF + f];
        SA += sa; SB += sb;
        cross = fmaf(sa, sb, cross);
        QA += sumsq[(aA * 8 + t) * FF + f];
        QB += sumsq[(aB * 8 + t) * FF + f];
    }
    const float invTN  = 1.0f / 2048.0f;    // 1/(T*N)
    const float invTNN = 1.0f / 262144.0f;  // 2/(T*N*N)
    float mA = SA * invTN, mB = SB * invTN;
    float m = mA + mB;
    float ey2 = (QA + QB) * invTN + cross * invTNN;
    float var = ey2 - m * m;
    float gf = br ? g2[f] : g1[f];
    float bf = br ? b2[f] : b1[f];
    float sc = gf * rsqrtf(var + 1e-5f);
    scale[br * FF + f] = sc;
    bias [br * FF + f] = bf - m * sc;
}

// ---------------------------------------------------------------------------
// Kernel 4: the streaming kernel. One wave per output row (t,br,i,j):
// lane holds channels (2*lane, 2*lane+1); relu(fma) -> 64-lane butterfly L1
// sum -> normalize -> nontemporal coalesced 8B/lane store (512 B/wave/row).
// grid = T*2*N = 4096 blocks x 256 threads (4 waves; wave w takes j in
// [64w, 64w+64)).
// ---------------------------------------------------------------------------
__global__ __launch_bounds__(256) void k_edge(
    const float* __restrict__ ws,
    const float* __restrict__ scale, const float* __restrict__ bias,
    float* __restrict__ out)
{
    const int bx = blockIdx.x;
    const int i  = bx & 255;
    const int br = (bx >> 8) & 1;
    const int t  = bx >> 9;
    const int tid = threadIdx.x;
    const int wave = tid >> 6, lane = tid & 63;

    const float* A = ws + (2 * br) * 262144 + (t * NN + i) * FF;
    const float* B = ws + (2 * br + 1) * 262144 + t * NN * FF;

    const vf2 a  = *(const vf2*)(A + 2 * lane);
    const vf2 s  = *(const vf2*)(scale + br * FF + 2 * lane);
    const vf2 bb = *(const vf2*)(bias  + br * FF + 2 * lane);
    const float c0 = fmaf(a.x, s.x, bb.x);
    const float c1 = fmaf(a.y, s.y, bb.y);

    vf2* orow = (vf2*)(out + ((size_t)(t * 2 + br) * NN + i) * NN * FF);

    #pragma unroll 4
    for (int jj = 0; jj < 64; ++jj) {
        const int j = wave * 64 + jj;
        const vf2 bv = *(const vf2*)(B + j * FF + 2 * lane);
        float v0 = fmaxf(fmaf(bv.x, s.x, c0), 0.0f);
        float v1 = fmaxf(fmaf(bv.y, s.y, c1), 0.0f);
        float sum = v0 + v1;
        #pragma unroll
        for (int off = 32; off > 0; off >>= 1)
            sum += __shfl_xor(sum, off, 64);
        float r = 1.0f / fmaxf(sum, 1e-12f);
        vf2 pk;
        if (j == i) {
            pk.x = 0.0f; pk.y = 0.0f;  // zeroed diagonal
        } else {
            pk.x = v0 * r; pk.y = v1 * r;
        }
        __builtin_nontemporal_store(pk, &orow[(size_t)j * 64 + lane]);
    }
}

// ---------------------------------------------------------------------------
extern "C" void kernel_launch(void* const* d_in, const int* in_sizes, int n_in,
                              void* d_out, int out_size, void* d_ws, size_t ws_size,
                              hipStream_t stream)
{
    const float* x  = (const float*)d_in[0];   // node_feats f32 [8,256,128]
    const float* w1 = (const float*)d_in[1];   // w1 f32 [128,256]
    const float* g1 = (const float*)d_in[2];
    const float* b1 = (const float*)d_in[3];
    const float* w2 = (const float*)d_in[4];
    const float* g2 = (const float*)d_in[5];
    const float* b2 = (const float*)d_in[6];

    float* ws    = (float*)d_ws;           // A1,B1,A2,B2: 4 x 262144 floats
    float* sums  = ws + 1048576;           // [4][8][128]
    float* sumsq = sums + 4096;            // [4][8][128]
    float* scale = sumsq + 4096;           // [2][128]
    float* bias  = scale + 256;            // [2][128]
    float* out = (float*)d_out;

    k_matmul<<<512, 128, 0, stream>>>(x, w1, w2, ws);
    k_stats <<<32, 256, 0, stream>>>(ws, sums, sumsq);
    k_scale <<<1, 256, 0, stream>>>(sums, sumsq, g1, b1, g2, b2, scale, bias);
    k_edge  <<<4096, 256, 0, stream>>>(ws, scale, bias, out);
}